// Round 13
// baseline (6797.514 us; speedup 1.0000x reference)
//
#include <hip/hip_runtime.h>

// ---- problem constants ----
#define Hdim 2048
#define Idim 5632
#define NEXP 8
#define NTOK 8192          // B*S = 4*2048
#define NROW 16384         // NTOK * top_k
#define RCAP 17408         // 136 tiles * 128 (max padded rows)
#define MTCAP 136

// ---- workspace meta layout (int indices) ----
#define MI_NTILES   0
#define MI_TOTAL    1
#define MI_COUNT    2      // [8]
#define MI_CURSOR   10     // [8]
#define MI_OFF      18     // [9]
#define MI_TILEEXP  32     // [136]
#define MI_ROWTOK   256    // [17408] token index per gathered row
#define MI_ROWW     17664  // [17408] float weight per gathered row
#define MI_TOPKID   35072  // [16384]
#define MI_TOPKW    51456  // [16384] floats
#define META_ZERO_BYTES (35072u * 4u)   // zero counts..row_weight each call

// ---- workspace buffer layout (byte offsets) ----
// Xg  bf16 [RCAP][Hdim]          = 68 MiB
// WgT bf16 [E][Idim][Hdim]       = 176 MiB   (transposed gate weights)
// WuT bf16 [E][Idim][Hdim]       = 176 MiB
// Hbuf bf16 [RCAP][Idim]         = 187 MiB
// WdT bf16 [E][Hdim][Idim]       = 176 MiB   -- ALIASES WgT (conv_d runs after gateup)
#define XG_OFF   (1ull << 19)
#define WGT_OFF  (72ull  << 20)
#define WUT_OFF  (248ull << 20)
#define HB_OFF   (424ull << 20)
#define WDT_OFF  WGT_OFF

typedef __attribute__((ext_vector_type(8))) short s8v;   // 8 bf16 = 4 VGPR
typedef __attribute__((ext_vector_type(4))) float f4v;   // MFMA acc

__device__ __forceinline__ unsigned short f2bf(float f) {  // RNE
  unsigned int u = __float_as_uint(f);
  u += 0x7fffu + ((u >> 16) & 1u);
  return (unsigned short)(u >> 16);
}
__device__ __forceinline__ unsigned int pack2(float lo, float hi) { // truncate, 2 bf16 in 1 dword
  return (__float_as_uint(lo) >> 16) | (__float_as_uint(hi) & 0xffff0000u);
}
__device__ __forceinline__ void glds16(const void* gp, void* lp) {
  __builtin_amdgcn_global_load_lds(
      (const __attribute__((address_space(1))) void*)gp,
      (__attribute__((address_space(3))) void*)lp, 16, 0, 0);
}

// ---------------- router: logits, top-2, renorm weights, per-expert counts ----------------
__global__ __launch_bounds__(256) void router_kernel(
    const float* __restrict__ x, const float* __restrict__ Wr,
    const float* __restrict__ br, float* __restrict__ logits,
    int* __restrict__ meta)
{
  int wv = threadIdx.x >> 6, lane = threadIdx.x & 63;
  int t = blockIdx.x * 4 + wv;
  const float* xr = x + (size_t)t * Hdim;
  float acc[8];
#pragma unroll
  for (int e = 0; e < 8; ++e) acc[e] = 0.f;
  for (int i = lane; i < Hdim; i += 64) {
    float xv = xr[i];
    const float4 w0 = *(const float4*)(Wr + (size_t)i * 8);
    const float4 w1 = *(const float4*)(Wr + (size_t)i * 8 + 4);
    acc[0] += xv * w0.x; acc[1] += xv * w0.y; acc[2] += xv * w0.z; acc[3] += xv * w0.w;
    acc[4] += xv * w1.x; acc[5] += xv * w1.y; acc[6] += xv * w1.z; acc[7] += xv * w1.w;
  }
#pragma unroll
  for (int off = 32; off > 0; off >>= 1)
#pragma unroll
    for (int e = 0; e < 8; ++e) acc[e] += __shfl_down(acc[e], off);
  if (lane == 0) {
    float l[8];
#pragma unroll
    for (int e = 0; e < 8; ++e) { l[e] = acc[e] + br[e]; logits[(size_t)t * 8 + e] = l[e]; }
    int i1 = 0;
#pragma unroll
    for (int e = 1; e < 8; ++e) if (l[e] > l[i1]) i1 = e;
    int i2 = -1;
#pragma unroll
    for (int e = 0; e < 8; ++e) if (e != i1 && (i2 < 0 || l[e] > l[i2])) i2 = e;
    float p2 = __expf(l[i2] - l[i1]);     // softmax denom cancels in renorm
    float s = 1.f + p2;
    meta[MI_TOPKID + t * 2]     = i1;
    meta[MI_TOPKID + t * 2 + 1] = i2;
    float* tw = (float*)(meta + MI_TOPKW);
    tw[t * 2] = 1.f / s; tw[t * 2 + 1] = p2 / s;
    atomicAdd(&meta[MI_COUNT + i1], 1);
    atomicAdd(&meta[MI_COUNT + i2], 1);
  }
}

// ---------------- offsets: 128-aligned expert segments + tile->expert map ----------------
__global__ void offsets_kernel(int* __restrict__ meta)
{
  __shared__ int soff[9];
  if (threadIdx.x == 0) {
    int off = 0;
#pragma unroll
    for (int e = 0; e < 8; ++e) {
      soff[e] = off;
      meta[MI_OFF + e] = off;
      meta[MI_CURSOR + e] = off;
      int c = meta[MI_COUNT + e];
      off += (c + 127) & ~127;
    }
    soff[8] = off;
    meta[MI_OFF + 8] = off;
    meta[MI_TOTAL] = off;
    meta[MI_NTILES] = off >> 7;
  }
  __syncthreads();
  int tile = threadIdx.x;
  if (tile < MTCAP) {
    int r = tile << 7;
    int e = 7;
    for (int q = 7; q >= 0; --q) if (r < soff[q + 1]) e = q;
    meta[MI_TILEEXP + tile] = e;
  }
}

// ---------------- scatter: (token,k) -> gathered row ----------------
__global__ __launch_bounds__(256) void scatter_kernel(int* __restrict__ meta)
{
  int idx = blockIdx.x * 256 + threadIdx.x;           // < 16384
  int e = meta[MI_TOPKID + idx];
  float w = ((const float*)(meta + MI_TOPKW))[idx];
  int pos = atomicAdd(&meta[MI_CURSOR + e], 1);
  meta[MI_ROWTOK + pos] = idx >> 1;
  ((float*)(meta + MI_ROWW))[pos] = w;
}

// ---------------- gather: x rows -> bf16 Xg in expert order ----------------
__global__ __launch_bounds__(256) void gather_kernel(
    const float* __restrict__ x, short* __restrict__ Xg,
    const int* __restrict__ meta)
{
  int r = blockIdx.x;
  int tok = meta[MI_ROWTOK + r];                       // 0 for pad rows (weight 0)
  int i = threadIdx.x * 8;
  const float* src = x + (size_t)tok * Hdim + i;
  float4 a = *(const float4*)src;
  float4 b = *(const float4*)(src + 4);
  union { s8v v; unsigned short us[8]; } o;
  o.us[0] = f2bf(a.x); o.us[1] = f2bf(a.y); o.us[2] = f2bf(a.z); o.us[3] = f2bf(a.w);
  o.us[4] = f2bf(b.x); o.us[5] = f2bf(b.y); o.us[6] = f2bf(b.z); o.us[7] = f2bf(b.w);
  *(s8v*)(Xg + (size_t)r * Hdim + i) = o.v;
}

// ---------------- transpose-convert v2: T[e][n][k] (bf16) = W[e][k][n] (fp32) ----------------
__global__ __launch_bounds__(256) void convT_kernel(
    const float* __restrict__ W, short* __restrict__ T, int K, int N)
{
  __shared__ float lds[64 * 66];
  int ntn = N >> 6, ntk = K >> 6;
  int per_e = ntn * ntk;
  int e = blockIdx.x / per_e;
  int r = blockIdx.x % per_e;
  int tn = r % ntn, tk = r / ntn;
  const float* We = W + (size_t)e * K * N + (size_t)(tk << 6) * N + (tn << 6);
  short* Te = T + (size_t)e * K * N + (size_t)(tn << 6) * K + (tk << 6);
  int tid = threadIdx.x;

  int k = tid >> 4;            // 16 rows per pass
  int n4 = (tid & 15) << 2;
#pragma unroll
  for (int p = 0; p < 4; ++p) {
    int kk = (p << 4) + k;
    float4 v = *(const float4*)(We + (size_t)kk * N + n4);
    lds[(n4 + 0) * 66 + kk] = v.x;
    lds[(n4 + 1) * 66 + kk] = v.y;
    lds[(n4 + 2) * 66 + kk] = v.z;
    lds[(n4 + 3) * 66 + kk] = v.w;
  }
  __syncthreads();

  int n = tid >> 3;            // 32 rows per pass
  int kp = (tid & 7) << 3;
#pragma unroll
  for (int p = 0; p < 2; ++p) {
    int nn = (p << 5) + n;
    const float* row = &lds[nn * 66 + kp];
    uint4 o;
    o.x = pack2(row[0], row[1]);
    o.y = pack2(row[2], row[3]);
    o.z = pack2(row[4], row[5]);
    o.w = pack2(row[6], row[7]);
    *(uint4*)(Te + (size_t)nn * K + kp) = o;
  }
}

// ======== GEMMs: 128x256 tile, 8 waves (2Mx4N), BK=64, one barrier-pair per 64-K ========
// R12's proven XOR 16B-slot swizzle (pre-swizzled global source, swizzled ds_read).
// 512 MFMA per barrier-pair (2x R12); A-tile staged once per 256 output cols.

// ---------------- pass A: h = silu(Xg@Wg[e]) * (Xg@Wu[e]) -> bf16 Hbuf ----------------
// LDS: A 16KB + G 32KB + U 32KB = 80KB -> 2 blocks/CU (16 waves, 50%).
__global__ __launch_bounds__(512, 4) void gateup_kernel(
    const short* __restrict__ Xg, const short* __restrict__ WgT,
    const short* __restrict__ WuT, short* __restrict__ Hbuf,
    const int* __restrict__ meta)
{
  const int NT = Idim / 256;                 // 22
  const int NWG = MTCAP * NT;                // 2992 = 8 * 374
  int bid = (blockIdx.x & 7) * (NWG / 8) + (blockIdx.x >> 3);  // XCD-bijective
  int chunk = bid / (8 * NT);
  int rem   = bid % (8 * NT);
  int mtile = chunk * 8 + (rem & 7);         // 8 M-tiles per chunk share weight panels
  int ntile = rem >> 3;
  if (mtile >= meta[MI_NTILES]) return;
  int e = meta[MI_TILEEXP + mtile];
  int n0 = ntile * 256;

  __shared__ short sA [128 * 64];            // 16 KB
  __shared__ short sBg[256 * 64];            // 32 KB
  __shared__ short sBu[256 * 64];            // 32 KB

  int tid = threadIdx.x;
  int lane = tid & 63, wv = tid >> 6;
  int wm = wv >> 2, wn = wv & 3;             // 2M x 4N, per-wave out 64x64 (g and u)
  int lr = lane & 15, lg = lane >> 4;
  int ldst = wv * 512;                       // wave-uniform dest (shorts) within round

  // staging: row-in-round = tid>>3 (0..63), pre-swizzled k-slot
  int srow = tid >> 3;
  int kc = ((tid & 7) ^ (srow & 7)) * 8;     // global k-chunk for physical slot tid&7
  const short* pA = Xg  + (size_t)(mtile * 128 + srow) * Hdim + kc;
  const short* pG = WgT + (size_t)e * Idim * Hdim + (size_t)(n0 + srow) * Hdim + kc;
  const short* pU = WuT + (size_t)e * Idim * Hdim + (size_t)(n0 + srow) * Hdim + kc;

  // swizzled fragment offsets: row R, k-half ks, chunk c = ks*4+lg -> slot c^(R&7)
  int aoff[4][2], boff[4][2];
#pragma unroll
  for (int mi = 0; mi < 4; ++mi) {
    int R = wm * 64 + mi * 16 + lr;
#pragma unroll
    for (int ks = 0; ks < 2; ++ks) aoff[mi][ks] = R * 64 + (((ks * 4 + lg) ^ (R & 7)) << 3);
  }
#pragma unroll
  for (int ni = 0; ni < 4; ++ni) {
    int R = wn * 64 + ni * 16 + lr;
#pragma unroll
    for (int ks = 0; ks < 2; ++ks) boff[ni][ks] = R * 64 + (((ks * 4 + lg) ^ (R & 7)) << 3);
  }

  f4v accg[4][4], accu[4][4];
  f4v z = {0.f, 0.f, 0.f, 0.f};
#pragma unroll
  for (int a1 = 0; a1 < 4; ++a1)
#pragma unroll
    for (int b1 = 0; b1 < 4; ++b1) { accg[a1][b1] = z; accu[a1][b1] = z; }

  for (int kt = 0; kt < Hdim / 64; ++kt) {   // 32 iters: 10 glds/thread, 512 MFMA/wave-set
    size_t k0 = (size_t)kt * 64;
#pragma unroll
    for (int r = 0; r < 2; ++r) {            // A: 2 rounds x 64 rows
      glds16(pA + (size_t)(r * 64) * Hdim + k0, &sA[r * 4096 + ldst]);
    }
#pragma unroll
    for (int r = 0; r < 4; ++r) {            // B: 4 rounds x 64 rows each
      size_t go = (size_t)(r * 64) * Hdim + k0;
      int lo = r * 4096 + ldst;
      glds16(pG + go, &sBg[lo]);
      glds16(pU + go, &sBu[lo]);
    }
    __syncthreads();

    s8v a[4][2];
#pragma unroll
    for (int mi = 0; mi < 4; ++mi)
#pragma unroll
      for (int ks = 0; ks < 2; ++ks)
        a[mi][ks] = *(const s8v*)&sA[aoff[mi][ks]];
#pragma unroll
    for (int ni = 0; ni < 4; ++ni) {
      s8v bg0 = *(const s8v*)&sBg[boff[ni][0]];
      s8v bg1 = *(const s8v*)&sBg[boff[ni][1]];
      s8v bu0 = *(const s8v*)&sBu[boff[ni][0]];
      s8v bu1 = *(const s8v*)&sBu[boff[ni][1]];
#pragma unroll
      for (int mi = 0; mi < 4; ++mi) {
        accg[mi][ni] = __builtin_amdgcn_mfma_f32_16x16x32_bf16(a[mi][0], bg0, accg[mi][ni], 0, 0, 0);
        accg[mi][ni] = __builtin_amdgcn_mfma_f32_16x16x32_bf16(a[mi][1], bg1, accg[mi][ni], 0, 0, 0);
        accu[mi][ni] = __builtin_amdgcn_mfma_f32_16x16x32_bf16(a[mi][0], bu0, accu[mi][ni], 0, 0, 0);
        accu[mi][ni] = __builtin_amdgcn_mfma_f32_16x16x32_bf16(a[mi][1], bu1, accu[mi][ni], 0, 0, 0);
      }
    }
    __syncthreads();
  }

  // epilogue: h = silu(g)*u -> bf16  (C/D: col=lane&15, row=(lane>>4)*4+r)
  int row0 = mtile * 128 + wm * 64;
  int col0 = n0 + wn * 64;
#pragma unroll
  for (int mi = 0; mi < 4; ++mi) {
#pragma unroll
    for (int ni = 0; ni < 4; ++ni) {
      int col = col0 + ni * 16 + lr;
#pragma unroll
      for (int r = 0; r < 4; ++r) {
        int row = row0 + mi * 16 + lg * 4 + r;
        float g = accg[mi][ni][r], u = accu[mi][ni][r];
        float h = g / (1.f + __expf(-g)) * u;
        Hbuf[(size_t)row * Idim + col] = (short)f2bf(h);
      }
    }
  }
}

// ---------------- pass B: y = Hbuf@Wd[e]; out[token] += w*y (atomic) ----------------
// 128x256 tile; LDS A 16KB + B 32KB = 48KB.
__global__ __launch_bounds__(512, 4) void down_kernel(
    const short* __restrict__ Hbuf, const short* __restrict__ WdT,
    float* __restrict__ out, const int* __restrict__ meta)
{
  const int NT = Hdim / 256;                 // 8
  const int NWG = MTCAP * NT;                // 1088 = 8 * 136
  int bid = (blockIdx.x & 7) * (NWG / 8) + (blockIdx.x >> 3);  // XCD-bijective
  int chunk = bid / (8 * NT);
  int rem   = bid % (8 * NT);
  int mtile = chunk * 8 + (rem & 7);
  int ntile = rem >> 3;
  if (mtile >= meta[MI_NTILES]) return;
  int e = meta[MI_TILEEXP + mtile];
  int n0 = ntile * 256;

  __shared__ short sA[128 * 64];
  __shared__ short sB[256 * 64];

  int tid = threadIdx.x;
  int lane = tid & 63, wv = tid >> 6;
  int wm = wv >> 2, wn = wv & 3;
  int lr = lane & 15, lg = lane >> 4;
  int ldst = wv * 512;

  int srow = tid >> 3;
  int kc = ((tid & 7) ^ (srow & 7)) * 8;
  const short* pA = Hbuf + (size_t)(mtile * 128 + srow) * Idim + kc;
  const short* pB = WdT  + (size_t)e * Hdim * Idim + (size_t)(n0 + srow) * Idim + kc;

  int aoff[4][2], boff[4][2];
#pragma unroll
  for (int mi = 0; mi < 4; ++mi) {
    int R = wm * 64 + mi * 16 + lr;
#pragma unroll
    for (int ks = 0; ks < 2; ++ks) aoff[mi][ks] = R * 64 + (((ks * 4 + lg) ^ (R & 7)) << 3);
  }
#pragma unroll
  for (int ni = 0; ni < 4; ++ni) {
    int R = wn * 64 + ni * 16 + lr;
#pragma unroll
    for (int ks = 0; ks < 2; ++ks) boff[ni][ks] = R * 64 + (((ks * 4 + lg) ^ (R & 7)) << 3);
  }

  f4v acc[4][4];
  f4v z = {0.f, 0.f, 0.f, 0.f};
#pragma unroll
  for (int a1 = 0; a1 < 4; ++a1)
#pragma unroll
    for (int b1 = 0; b1 < 4; ++b1) acc[a1][b1] = z;

  for (int kt = 0; kt < Idim / 64; ++kt) {   // 88 iters
    size_t k0 = (size_t)kt * 64;
#pragma unroll
    for (int r = 0; r < 2; ++r)
      glds16(pA + (size_t)(r * 64) * Idim + k0, &sA[r * 4096 + ldst]);
#pragma unroll
    for (int r = 0; r < 4; ++r)
      glds16(pB + (size_t)(r * 64) * Idim + k0, &sB[r * 4096 + ldst]);
    __syncthreads();

    s8v a[4][2];
#pragma unroll
    for (int mi = 0; mi < 4; ++mi)
#pragma unroll
      for (int ks = 0; ks < 2; ++ks)
        a[mi][ks] = *(const s8v*)&sA[aoff[mi][ks]];
#pragma unroll
    for (int ni = 0; ni < 4; ++ni) {
      s8v b0 = *(const s8v*)&sB[boff[ni][0]];
      s8v b1 = *(const s8v*)&sB[boff[ni][1]];
#pragma unroll
      for (int mi = 0; mi < 4; ++mi) {
        acc[mi][ni] = __builtin_amdgcn_mfma_f32_16x16x32_bf16(a[mi][0], b0, acc[mi][ni], 0, 0, 0);
        acc[mi][ni] = __builtin_amdgcn_mfma_f32_16x16x32_bf16(a[mi][1], b1, acc[mi][ni], 0, 0, 0);
      }
    }
    __syncthreads();
  }

  int row0 = mtile * 128 + wm * 64;
  int col0 = n0 + wn * 64;
  const int* rowtok = meta + MI_ROWTOK;
  const float* roww = (const float*)(meta + MI_ROWW);
#pragma unroll
  for (int mi = 0; mi < 4; ++mi) {
#pragma unroll
    for (int r = 0; r < 4; ++r) {
      int row = row0 + mi * 16 + lg * 4 + r;
      int tok = rowtok[row];
      float w = roww[row];                    // 0 for pad rows
      float* orow = out + (size_t)tok * Hdim + col0 + lr;
#pragma unroll
      for (int ni = 0; ni < 4; ++ni)
        atomicAdd(orow + ni * 16, w * acc[mi][ni][r]);
    }
  }
}

extern "C" void kernel_launch(void* const* d_in, const int* in_sizes, int n_in,
                              void* d_out, int out_size, void* d_ws, size_t ws_size,
                              hipStream_t stream)
{
  (void)in_sizes; (void)n_in; (void)out_size; (void)ws_size;
  const float* x  = (const float*)d_in[0];
  const float* Wr = (const float*)d_in[1];
  const float* br = (const float*)d_in[2];
  const float* Wg = (const float*)d_in[3];
  const float* Wu = (const float*)d_in[4];
  const float* Wd = (const float*)d_in[5];
  float* out = (float*)d_out;
  float* logits = out + (size_t)NTOK * Hdim;        // output 1 region
  int* meta = (int*)d_ws;
  short* Xg   = (short*)((char*)d_ws + XG_OFF);
  short* WgT  = (short*)((char*)d_ws + WGT_OFF);
  short* WuT  = (short*)((char*)d_ws + WUT_OFF);
  short* WdT  = (short*)((char*)d_ws + WDT_OFF);    // aliases WgT
  short* Hbuf = (short*)((char*)d_ws + HB_OFF);

  hipMemsetAsync(d_out, 0, (size_t)NTOK * Hdim * sizeof(float), stream); // atomics accumulate
  hipMemsetAsync(d_ws, 0, META_ZERO_BYTES, stream);                      // counts + row tok/weight

  const int convBlocks = NEXP * (Idim / 64) * (Hdim / 64);               // 22528

  router_kernel <<<NTOK / 4, 256, 0, stream>>>(x, Wr, br, logits, meta);
  offsets_kernel<<<1, 256, 0, stream>>>(meta);
  scatter_kernel<<<NROW / 256, 256, 0, stream>>>(meta);
  gather_kernel <<<RCAP, 256, 0, stream>>>(x, Xg, meta);
  convT_kernel  <<<convBlocks, 256, 0, stream>>>(Wg, WgT, Hdim, Idim);
  convT_kernel  <<<convBlocks, 256, 0, stream>>>(Wu, WuT, Hdim, Idim);
  gateup_kernel <<<MTCAP * (Idim / 256), 512, 0, stream>>>(Xg, WgT, WuT, Hbuf, meta);
  convT_kernel  <<<convBlocks, 256, 0, stream>>>(Wd, WdT, Idim, Hdim);   // after gateup (aliases WgT)
  down_kernel   <<<MTCAP * (Hdim / 256), 512, 0, stream>>>(Hbuf, WdT, out, meta);
}

// Round 14
// 2278.334 us; speedup vs baseline: 2.9835x; 2.9835x over previous
//
#include <hip/hip_runtime.h>

// ---- problem constants ----
#define Hdim 2048
#define Idim 5632
#define NEXP 8
#define NTOK 8192          // B*S = 4*2048
#define NROW 16384         // NTOK * top_k
#define RCAP 17408         // 136 tiles * 128 (max padded rows)
#define MTCAP 136

// ---- workspace meta layout (int indices) ----
#define MI_NTILES   0
#define MI_TOTAL    1
#define MI_COUNT    2      // [8]
#define MI_CURSOR   10     // [8]
#define MI_OFF      18     // [9]
#define MI_TILEEXP  32     // [136]
#define MI_ROWTOK   256    // [17408] token index per gathered row
#define MI_ROWW     17664  // [17408] float weight per gathered row
#define MI_TOPKID   35072  // [16384]
#define MI_TOPKW    51456  // [16384] floats
#define META_ZERO_BYTES (35072u * 4u)   // zero counts..row_weight each call

// ---- workspace buffer layout (byte offsets) ----
// Xg  bf16 [RCAP][Hdim]          = 68 MiB
// WgT bf16 [E][Idim][Hdim]       = 176 MiB   (transposed gate weights)
// WuT bf16 [E][Idim][Hdim]       = 176 MiB
// Hbuf bf16 [RCAP][Idim]         = 187 MiB
// WdT bf16 [E][Hdim][Idim]       = 176 MiB   -- ALIASES WgT (conv_d runs after gateup)
#define XG_OFF   (1ull << 19)
#define WGT_OFF  (72ull  << 20)
#define WUT_OFF  (248ull << 20)
#define HB_OFF   (424ull << 20)
#define WDT_OFF  WGT_OFF

typedef __attribute__((ext_vector_type(8))) short s8v;   // 8 bf16 = 4 VGPR
typedef __attribute__((ext_vector_type(4))) float f4v;   // MFMA acc

__device__ __forceinline__ unsigned short f2bf(float f) {  // RNE
  unsigned int u = __float_as_uint(f);
  u += 0x7fffu + ((u >> 16) & 1u);
  return (unsigned short)(u >> 16);
}
__device__ __forceinline__ unsigned int pack2(float lo, float hi) { // truncate, 2 bf16 in 1 dword
  return (__float_as_uint(lo) >> 16) | (__float_as_uint(hi) & 0xffff0000u);
}
__device__ __forceinline__ void glds16(const void* gp, void* lp) {
  __builtin_amdgcn_global_load_lds(
      (const __attribute__((address_space(1))) void*)gp,
      (__attribute__((address_space(3))) void*)lp, 16, 0, 0);
}

// ---------------- router: logits, top-2, renorm weights, per-expert counts ----------------
__global__ __launch_bounds__(256) void router_kernel(
    const float* __restrict__ x, const float* __restrict__ Wr,
    const float* __restrict__ br, float* __restrict__ logits,
    int* __restrict__ meta)
{
  int wv = threadIdx.x >> 6, lane = threadIdx.x & 63;
  int t = blockIdx.x * 4 + wv;
  const float* xr = x + (size_t)t * Hdim;
  float acc[8];
#pragma unroll
  for (int e = 0; e < 8; ++e) acc[e] = 0.f;
  for (int i = lane; i < Hdim; i += 64) {
    float xv = xr[i];
    const float4 w0 = *(const float4*)(Wr + (size_t)i * 8);
    const float4 w1 = *(const float4*)(Wr + (size_t)i * 8 + 4);
    acc[0] += xv * w0.x; acc[1] += xv * w0.y; acc[2] += xv * w0.z; acc[3] += xv * w0.w;
    acc[4] += xv * w1.x; acc[5] += xv * w1.y; acc[6] += xv * w1.z; acc[7] += xv * w1.w;
  }
#pragma unroll
  for (int off = 32; off > 0; off >>= 1)
#pragma unroll
    for (int e = 0; e < 8; ++e) acc[e] += __shfl_down(acc[e], off);
  if (lane == 0) {
    float l[8];
#pragma unroll
    for (int e = 0; e < 8; ++e) { l[e] = acc[e] + br[e]; logits[(size_t)t * 8 + e] = l[e]; }
    int i1 = 0;
#pragma unroll
    for (int e = 1; e < 8; ++e) if (l[e] > l[i1]) i1 = e;
    int i2 = -1;
#pragma unroll
    for (int e = 0; e < 8; ++e) if (e != i1 && (i2 < 0 || l[e] > l[i2])) i2 = e;
    float p2 = __expf(l[i2] - l[i1]);     // softmax denom cancels in renorm
    float s = 1.f + p2;
    meta[MI_TOPKID + t * 2]     = i1;
    meta[MI_TOPKID + t * 2 + 1] = i2;
    float* tw = (float*)(meta + MI_TOPKW);
    tw[t * 2] = 1.f / s; tw[t * 2 + 1] = p2 / s;
    atomicAdd(&meta[MI_COUNT + i1], 1);
    atomicAdd(&meta[MI_COUNT + i2], 1);
  }
}

// ---------------- offsets: 128-aligned expert segments + tile->expert map ----------------
__global__ void offsets_kernel(int* __restrict__ meta)
{
  __shared__ int soff[9];
  if (threadIdx.x == 0) {
    int off = 0;
#pragma unroll
    for (int e = 0; e < 8; ++e) {
      soff[e] = off;
      meta[MI_OFF + e] = off;
      meta[MI_CURSOR + e] = off;
      int c = meta[MI_COUNT + e];
      off += (c + 127) & ~127;
    }
    soff[8] = off;
    meta[MI_OFF + 8] = off;
    meta[MI_TOTAL] = off;
    meta[MI_NTILES] = off >> 7;
  }
  __syncthreads();
  int tile = threadIdx.x;
  if (tile < MTCAP) {
    int r = tile << 7;
    int e = 7;
    for (int q = 7; q >= 0; --q) if (r < soff[q + 1]) e = q;
    meta[MI_TILEEXP + tile] = e;
  }
}

// ---------------- scatter: (token,k) -> gathered row ----------------
__global__ __launch_bounds__(256) void scatter_kernel(int* __restrict__ meta)
{
  int idx = blockIdx.x * 256 + threadIdx.x;           // < 16384
  int e = meta[MI_TOPKID + idx];
  float w = ((const float*)(meta + MI_TOPKW))[idx];
  int pos = atomicAdd(&meta[MI_CURSOR + e], 1);
  meta[MI_ROWTOK + pos] = idx >> 1;
  ((float*)(meta + MI_ROWW))[pos] = w;
}

// ---------------- gather: x rows -> bf16 Xg in expert order ----------------
__global__ __launch_bounds__(256) void gather_kernel(
    const float* __restrict__ x, short* __restrict__ Xg,
    const int* __restrict__ meta)
{
  int r = blockIdx.x;
  int tok = meta[MI_ROWTOK + r];                       // 0 for pad rows (weight 0)
  int i = threadIdx.x * 8;
  const float* src = x + (size_t)tok * Hdim + i;
  float4 a = *(const float4*)src;
  float4 b = *(const float4*)(src + 4);
  union { s8v v; unsigned short us[8]; } o;
  o.us[0] = f2bf(a.x); o.us[1] = f2bf(a.y); o.us[2] = f2bf(a.z); o.us[3] = f2bf(a.w);
  o.us[4] = f2bf(b.x); o.us[5] = f2bf(b.y); o.us[6] = f2bf(b.z); o.us[7] = f2bf(b.w);
  *(s8v*)(Xg + (size_t)r * Hdim + i) = o.v;
}

// ---------------- transpose-convert v2: T[e][n][k] (bf16) = W[e][k][n] (fp32) ----------------
__global__ __launch_bounds__(256) void convT_kernel(
    const float* __restrict__ W, short* __restrict__ T, int K, int N)
{
  __shared__ float lds[64 * 66];
  int ntn = N >> 6, ntk = K >> 6;
  int per_e = ntn * ntk;
  int e = blockIdx.x / per_e;
  int r = blockIdx.x % per_e;
  int tn = r % ntn, tk = r / ntn;
  const float* We = W + (size_t)e * K * N + (size_t)(tk << 6) * N + (tn << 6);
  short* Te = T + (size_t)e * K * N + (size_t)(tn << 6) * K + (tk << 6);
  int tid = threadIdx.x;

  int k = tid >> 4;            // 16 rows per pass
  int n4 = (tid & 15) << 2;
#pragma unroll
  for (int p = 0; p < 4; ++p) {
    int kk = (p << 4) + k;
    float4 v = *(const float4*)(We + (size_t)kk * N + n4);
    lds[(n4 + 0) * 66 + kk] = v.x;
    lds[(n4 + 1) * 66 + kk] = v.y;
    lds[(n4 + 2) * 66 + kk] = v.z;
    lds[(n4 + 3) * 66 + kk] = v.w;
  }
  __syncthreads();

  int n = tid >> 3;            // 32 rows per pass
  int kp = (tid & 7) << 3;
#pragma unroll
  for (int p = 0; p < 2; ++p) {
    int nn = (p << 5) + n;
    const float* row = &lds[nn * 66 + kp];
    uint4 o;
    o.x = pack2(row[0], row[1]);
    o.y = pack2(row[2], row[3]);
    o.z = pack2(row[4], row[5]);
    o.w = pack2(row[6], row[7]);
    *(uint4*)(Te + (size_t)nn * K + kp) = o;
  }
}

// ======== GEMMs: 128x256 tile, 8 waves (2Mx4N), BK=64, one barrier-pair per 64-K ========
// R12's proven XOR 16B-slot swizzle (pre-swizzled global source, swizzled ds_read).
// 512 MFMA per barrier-pair (2x R12); A-tile staged once per 256 output cols.
// launch_bounds(512,2): 256-reg combined VGPR+AGPR cap (R13's (512,4) = 128 cap ->
// the 128-AGPR accumulator alone filled it -> total scratch spill, 15 GB writes).

// ---------------- pass A: h = silu(Xg@Wg[e]) * (Xg@Wu[e]) -> bf16 Hbuf ----------------
// LDS: A 16KB + G 32KB + U 32KB = 80KB.
__global__ __launch_bounds__(512, 2) void gateup_kernel(
    const short* __restrict__ Xg, const short* __restrict__ WgT,
    const short* __restrict__ WuT, short* __restrict__ Hbuf,
    const int* __restrict__ meta)
{
  const int NT = Idim / 256;                 // 22
  const int NWG = MTCAP * NT;                // 2992 = 8 * 374
  int bid = (blockIdx.x & 7) * (NWG / 8) + (blockIdx.x >> 3);  // XCD-bijective
  int chunk = bid / (8 * NT);
  int rem   = bid % (8 * NT);
  int mtile = chunk * 8 + (rem & 7);         // 8 M-tiles per chunk share weight panels
  int ntile = rem >> 3;
  if (mtile >= meta[MI_NTILES]) return;
  int e = meta[MI_TILEEXP + mtile];
  int n0 = ntile * 256;

  __shared__ short sA [128 * 64];            // 16 KB
  __shared__ short sBg[256 * 64];            // 32 KB
  __shared__ short sBu[256 * 64];            // 32 KB

  int tid = threadIdx.x;
  int lane = tid & 63, wv = tid >> 6;
  int wm = wv >> 2, wn = wv & 3;             // 2M x 4N, per-wave out 64x64 (g and u)
  int lr = lane & 15, lg = lane >> 4;
  int ldst = wv * 512;                       // wave-uniform dest (shorts) within round

  // staging: row-in-round = tid>>3 (0..63), pre-swizzled k-slot
  int srow = tid >> 3;
  int kc = ((tid & 7) ^ (srow & 7)) * 8;     // global k-chunk for physical slot tid&7
  const short* pA = Xg  + (size_t)(mtile * 128 + srow) * Hdim + kc;
  const short* pG = WgT + (size_t)e * Idim * Hdim + (size_t)(n0 + srow) * Hdim + kc;
  const short* pU = WuT + (size_t)e * Idim * Hdim + (size_t)(n0 + srow) * Hdim + kc;

  // swizzled fragment offsets: row R, k-half ks, chunk c = ks*4+lg -> slot c^(R&7)
  int aoff[4][2], boff[4][2];
#pragma unroll
  for (int mi = 0; mi < 4; ++mi) {
    int R = wm * 64 + mi * 16 + lr;
#pragma unroll
    for (int ks = 0; ks < 2; ++ks) aoff[mi][ks] = R * 64 + (((ks * 4 + lg) ^ (R & 7)) << 3);
  }
#pragma unroll
  for (int ni = 0; ni < 4; ++ni) {
    int R = wn * 64 + ni * 16 + lr;
#pragma unroll
    for (int ks = 0; ks < 2; ++ks) boff[ni][ks] = R * 64 + (((ks * 4 + lg) ^ (R & 7)) << 3);
  }

  f4v accg[4][4], accu[4][4];
  f4v z = {0.f, 0.f, 0.f, 0.f};
#pragma unroll
  for (int a1 = 0; a1 < 4; ++a1)
#pragma unroll
    for (int b1 = 0; b1 < 4; ++b1) { accg[a1][b1] = z; accu[a1][b1] = z; }

  for (int kt = 0; kt < Hdim / 64; ++kt) {   // 32 iters: 10 glds/thread, 512 MFMA/block
    size_t k0 = (size_t)kt * 64;
#pragma unroll
    for (int r = 0; r < 2; ++r) {            // A: 2 rounds x 64 rows
      glds16(pA + (size_t)(r * 64) * Hdim + k0, &sA[r * 4096 + ldst]);
    }
#pragma unroll
    for (int r = 0; r < 4; ++r) {            // B: 4 rounds x 64 rows each
      size_t go = (size_t)(r * 64) * Hdim + k0;
      int lo = r * 4096 + ldst;
      glds16(pG + go, &sBg[lo]);
      glds16(pU + go, &sBu[lo]);
    }
    __syncthreads();

    s8v a[4][2];
#pragma unroll
    for (int mi = 0; mi < 4; ++mi)
#pragma unroll
      for (int ks = 0; ks < 2; ++ks)
        a[mi][ks] = *(const s8v*)&sA[aoff[mi][ks]];
#pragma unroll
    for (int ni = 0; ni < 4; ++ni) {
      s8v bg0 = *(const s8v*)&sBg[boff[ni][0]];
      s8v bg1 = *(const s8v*)&sBg[boff[ni][1]];
      s8v bu0 = *(const s8v*)&sBu[boff[ni][0]];
      s8v bu1 = *(const s8v*)&sBu[boff[ni][1]];
#pragma unroll
      for (int mi = 0; mi < 4; ++mi) {
        accg[mi][ni] = __builtin_amdgcn_mfma_f32_16x16x32_bf16(a[mi][0], bg0, accg[mi][ni], 0, 0, 0);
        accg[mi][ni] = __builtin_amdgcn_mfma_f32_16x16x32_bf16(a[mi][1], bg1, accg[mi][ni], 0, 0, 0);
        accu[mi][ni] = __builtin_amdgcn_mfma_f32_16x16x32_bf16(a[mi][0], bu0, accu[mi][ni], 0, 0, 0);
        accu[mi][ni] = __builtin_amdgcn_mfma_f32_16x16x32_bf16(a[mi][1], bu1, accu[mi][ni], 0, 0, 0);
      }
    }
    __syncthreads();
  }

  // epilogue: h = silu(g)*u -> bf16  (C/D: col=lane&15, row=(lane>>4)*4+r)
  int row0 = mtile * 128 + wm * 64;
  int col0 = n0 + wn * 64;
#pragma unroll
  for (int mi = 0; mi < 4; ++mi) {
#pragma unroll
    for (int ni = 0; ni < 4; ++ni) {
      int col = col0 + ni * 16 + lr;
#pragma unroll
      for (int r = 0; r < 4; ++r) {
        int row = row0 + mi * 16 + lg * 4 + r;
        float g = accg[mi][ni][r], u = accu[mi][ni][r];
        float h = g / (1.f + __expf(-g)) * u;
        Hbuf[(size_t)row * Idim + col] = (short)f2bf(h);
      }
    }
  }
}

// ---------------- pass B: y = Hbuf@Wd[e]; out[token] += w*y (atomic) ----------------
// 128x256 tile; LDS A 16KB + B 32KB = 48KB.
__global__ __launch_bounds__(512, 2) void down_kernel(
    const short* __restrict__ Hbuf, const short* __restrict__ WdT,
    float* __restrict__ out, const int* __restrict__ meta)
{
  const int NT = Hdim / 256;                 // 8
  const int NWG = MTCAP * NT;                // 1088 = 8 * 136
  int bid = (blockIdx.x & 7) * (NWG / 8) + (blockIdx.x >> 3);  // XCD-bijective
  int chunk = bid / (8 * NT);
  int rem   = bid % (8 * NT);
  int mtile = chunk * 8 + (rem & 7);
  int ntile = rem >> 3;
  if (mtile >= meta[MI_NTILES]) return;
  int e = meta[MI_TILEEXP + mtile];
  int n0 = ntile * 256;

  __shared__ short sA[128 * 64];
  __shared__ short sB[256 * 64];

  int tid = threadIdx.x;
  int lane = tid & 63, wv = tid >> 6;
  int wm = wv >> 2, wn = wv & 3;
  int lr = lane & 15, lg = lane >> 4;
  int ldst = wv * 512;

  int srow = tid >> 3;
  int kc = ((tid & 7) ^ (srow & 7)) * 8;
  const short* pA = Hbuf + (size_t)(mtile * 128 + srow) * Idim + kc;
  const short* pB = WdT  + (size_t)e * Hdim * Idim + (size_t)(n0 + srow) * Idim + kc;

  int aoff[4][2], boff[4][2];
#pragma unroll
  for (int mi = 0; mi < 4; ++mi) {
    int R = wm * 64 + mi * 16 + lr;
#pragma unroll
    for (int ks = 0; ks < 2; ++ks) aoff[mi][ks] = R * 64 + (((ks * 4 + lg) ^ (R & 7)) << 3);
  }
#pragma unroll
  for (int ni = 0; ni < 4; ++ni) {
    int R = wn * 64 + ni * 16 + lr;
#pragma unroll
    for (int ks = 0; ks < 2; ++ks) boff[ni][ks] = R * 64 + (((ks * 4 + lg) ^ (R & 7)) << 3);
  }

  f4v acc[4][4];
  f4v z = {0.f, 0.f, 0.f, 0.f};
#pragma unroll
  for (int a1 = 0; a1 < 4; ++a1)
#pragma unroll
    for (int b1 = 0; b1 < 4; ++b1) acc[a1][b1] = z;

  for (int kt = 0; kt < Idim / 64; ++kt) {   // 88 iters
    size_t k0 = (size_t)kt * 64;
#pragma unroll
    for (int r = 0; r < 2; ++r)
      glds16(pA + (size_t)(r * 64) * Idim + k0, &sA[r * 4096 + ldst]);
#pragma unroll
    for (int r = 0; r < 4; ++r)
      glds16(pB + (size_t)(r * 64) * Idim + k0, &sB[r * 4096 + ldst]);
    __syncthreads();

    s8v a[4][2];
#pragma unroll
    for (int mi = 0; mi < 4; ++mi)
#pragma unroll
      for (int ks = 0; ks < 2; ++ks)
        a[mi][ks] = *(const s8v*)&sA[aoff[mi][ks]];
#pragma unroll
    for (int ni = 0; ni < 4; ++ni) {
      s8v b0 = *(const s8v*)&sB[boff[ni][0]];
      s8v b1 = *(const s8v*)&sB[boff[ni][1]];
#pragma unroll
      for (int mi = 0; mi < 4; ++mi) {
        acc[mi][ni] = __builtin_amdgcn_mfma_f32_16x16x32_bf16(a[mi][0], b0, acc[mi][ni], 0, 0, 0);
        acc[mi][ni] = __builtin_amdgcn_mfma_f32_16x16x32_bf16(a[mi][1], b1, acc[mi][ni], 0, 0, 0);
      }
    }
    __syncthreads();
  }

  int row0 = mtile * 128 + wm * 64;
  int col0 = n0 + wn * 64;
  const int* rowtok = meta + MI_ROWTOK;
  const float* roww = (const float*)(meta + MI_ROWW);
#pragma unroll
  for (int mi = 0; mi < 4; ++mi) {
#pragma unroll
    for (int r = 0; r < 4; ++r) {
      int row = row0 + mi * 16 + lg * 4 + r;
      int tok = rowtok[row];
      float w = roww[row];                    // 0 for pad rows
      float* orow = out + (size_t)tok * Hdim + col0 + lr;
#pragma unroll
      for (int ni = 0; ni < 4; ++ni)
        atomicAdd(orow + ni * 16, w * acc[mi][ni][r]);
    }
  }
}

extern "C" void kernel_launch(void* const* d_in, const int* in_sizes, int n_in,
                              void* d_out, int out_size, void* d_ws, size_t ws_size,
                              hipStream_t stream)
{
  (void)in_sizes; (void)n_in; (void)out_size; (void)ws_size;
  const float* x  = (const float*)d_in[0];
  const float* Wr = (const float*)d_in[1];
  const float* br = (const float*)d_in[2];
  const float* Wg = (const float*)d_in[3];
  const float* Wu = (const float*)d_in[4];
  const float* Wd = (const float*)d_in[5];
  float* out = (float*)d_out;
  float* logits = out + (size_t)NTOK * Hdim;        // output 1 region
  int* meta = (int*)d_ws;
  short* Xg   = (short*)((char*)d_ws + XG_OFF);
  short* WgT  = (short*)((char*)d_ws + WGT_OFF);
  short* WuT  = (short*)((char*)d_ws + WUT_OFF);
  short* WdT  = (short*)((char*)d_ws + WDT_OFF);    // aliases WgT
  short* Hbuf = (short*)((char*)d_ws + HB_OFF);

  hipMemsetAsync(d_out, 0, (size_t)NTOK * Hdim * sizeof(float), stream); // atomics accumulate
  hipMemsetAsync(d_ws, 0, META_ZERO_BYTES, stream);                      // counts + row tok/weight

  const int convBlocks = NEXP * (Idim / 64) * (Hdim / 64);               // 22528

  router_kernel <<<NTOK / 4, 256, 0, stream>>>(x, Wr, br, logits, meta);
  offsets_kernel<<<1, 256, 0, stream>>>(meta);
  scatter_kernel<<<NROW / 256, 256, 0, stream>>>(meta);
  gather_kernel <<<RCAP, 256, 0, stream>>>(x, Xg, meta);
  convT_kernel  <<<convBlocks, 256, 0, stream>>>(Wg, WgT, Hdim, Idim);
  convT_kernel  <<<convBlocks, 256, 0, stream>>>(Wu, WuT, Hdim, Idim);
  gateup_kernel <<<MTCAP * (Idim / 256), 512, 0, stream>>>(Xg, WgT, WuT, Hbuf, meta);
  convT_kernel  <<<convBlocks, 256, 0, stream>>>(Wd, WdT, Idim, Hdim);   // after gateup (aliases WgT)
  down_kernel   <<<MTCAP * (Hdim / 256), 512, 0, stream>>>(Hbuf, WdT, out, meta);
}

// Round 15
// 1937.234 us; speedup vs baseline: 3.5089x; 1.1761x over previous
//
#include <hip/hip_runtime.h>

// ---- problem constants ----
#define Hdim 2048
#define Idim 5632
#define NEXP 8
#define NTOK 8192          // B*S = 4*2048
#define NROW 16384         // NTOK * top_k
#define RCAP 17408         // 136 tiles * 128 (max padded rows)
#define MTCAP 136

// ---- workspace meta layout (int indices) ----
#define MI_NTILES   0
#define MI_TOTAL    1
#define MI_COUNT    2      // [8]
#define MI_CURSOR   10     // [8]
#define MI_OFF      18     // [9]
#define MI_TILEEXP  32     // [136]
#define MI_ROWTOK   256    // [17408] token index per gathered row
#define MI_ROWW     17664  // [17408] float weight per gathered row
#define MI_TOPKID   35072  // [16384]
#define MI_TOPKW    51456  // [16384] floats
#define META_ZERO_BYTES (35072u * 4u)   // zero counts..row_weight each call

// ---- workspace buffer layout (byte offsets) ----
// Xg  bf16 [RCAP][Hdim]          = 68 MiB
// WgT bf16 [E][Idim][Hdim]       = 176 MiB   (transposed gate weights)
// WuT bf16 [E][Idim][Hdim]       = 176 MiB
// Hbuf bf16 [RCAP][Idim]         = 187 MiB
// WdT bf16 [E][Hdim][Idim]       = 176 MiB   -- ALIASES WgT (conv_d runs after gateup)
#define XG_OFF   (1ull << 19)
#define WGT_OFF  (72ull  << 20)
#define WUT_OFF  (248ull << 20)
#define HB_OFF   (424ull << 20)
#define WDT_OFF  WGT_OFF

typedef __attribute__((ext_vector_type(8))) short s8v;   // 8 bf16 = 4 VGPR
typedef __attribute__((ext_vector_type(4))) float f4v;   // MFMA acc

__device__ __forceinline__ unsigned short f2bf(float f) {  // RNE
  unsigned int u = __float_as_uint(f);
  u += 0x7fffu + ((u >> 16) & 1u);
  return (unsigned short)(u >> 16);
}
__device__ __forceinline__ unsigned int pack2(float lo, float hi) { // truncate, 2 bf16 in 1 dword
  return (__float_as_uint(lo) >> 16) | (__float_as_uint(hi) & 0xffff0000u);
}
__device__ __forceinline__ void glds16(const void* gp, void* lp) {
  __builtin_amdgcn_global_load_lds(
      (const __attribute__((address_space(1))) void*)gp,
      (__attribute__((address_space(3))) void*)lp, 16, 0, 0);
}

// ---------------- router: logits, top-2, renorm weights, per-expert counts ----------------
__global__ __launch_bounds__(256) void router_kernel(
    const float* __restrict__ x, const float* __restrict__ Wr,
    const float* __restrict__ br, float* __restrict__ logits,
    int* __restrict__ meta)
{
  int wv = threadIdx.x >> 6, lane = threadIdx.x & 63;
  int t = blockIdx.x * 4 + wv;
  const float* xr = x + (size_t)t * Hdim;
  float acc[8];
#pragma unroll
  for (int e = 0; e < 8; ++e) acc[e] = 0.f;
  for (int i = lane; i < Hdim; i += 64) {
    float xv = xr[i];
    const float4 w0 = *(const float4*)(Wr + (size_t)i * 8);
    const float4 w1 = *(const float4*)(Wr + (size_t)i * 8 + 4);
    acc[0] += xv * w0.x; acc[1] += xv * w0.y; acc[2] += xv * w0.z; acc[3] += xv * w0.w;
    acc[4] += xv * w1.x; acc[5] += xv * w1.y; acc[6] += xv * w1.z; acc[7] += xv * w1.w;
  }
#pragma unroll
  for (int off = 32; off > 0; off >>= 1)
#pragma unroll
    for (int e = 0; e < 8; ++e) acc[e] += __shfl_down(acc[e], off);
  if (lane == 0) {
    float l[8];
#pragma unroll
    for (int e = 0; e < 8; ++e) { l[e] = acc[e] + br[e]; logits[(size_t)t * 8 + e] = l[e]; }
    int i1 = 0;
#pragma unroll
    for (int e = 1; e < 8; ++e) if (l[e] > l[i1]) i1 = e;
    int i2 = -1;
#pragma unroll
    for (int e = 0; e < 8; ++e) if (e != i1 && (i2 < 0 || l[e] > l[i2])) i2 = e;
    float p2 = __expf(l[i2] - l[i1]);     // softmax denom cancels in renorm
    float s = 1.f + p2;
    meta[MI_TOPKID + t * 2]     = i1;
    meta[MI_TOPKID + t * 2 + 1] = i2;
    float* tw = (float*)(meta + MI_TOPKW);
    tw[t * 2] = 1.f / s; tw[t * 2 + 1] = p2 / s;
    atomicAdd(&meta[MI_COUNT + i1], 1);
    atomicAdd(&meta[MI_COUNT + i2], 1);
  }
}

// ---------------- offsets: 128-aligned expert segments + tile->expert map ----------------
__global__ void offsets_kernel(int* __restrict__ meta)
{
  __shared__ int soff[9];
  if (threadIdx.x == 0) {
    int off = 0;
#pragma unroll
    for (int e = 0; e < 8; ++e) {
      soff[e] = off;
      meta[MI_OFF + e] = off;
      meta[MI_CURSOR + e] = off;
      int c = meta[MI_COUNT + e];
      off += (c + 127) & ~127;
    }
    soff[8] = off;
    meta[MI_OFF + 8] = off;
    meta[MI_TOTAL] = off;
    meta[MI_NTILES] = off >> 7;
  }
  __syncthreads();
  int tile = threadIdx.x;
  if (tile < MTCAP) {
    int r = tile << 7;
    int e = 7;
    for (int q = 7; q >= 0; --q) if (r < soff[q + 1]) e = q;
    meta[MI_TILEEXP + tile] = e;
  }
}

// ---------------- scatter: (token,k) -> gathered row ----------------
__global__ __launch_bounds__(256) void scatter_kernel(int* __restrict__ meta)
{
  int idx = blockIdx.x * 256 + threadIdx.x;           // < 16384
  int e = meta[MI_TOPKID + idx];
  float w = ((const float*)(meta + MI_TOPKW))[idx];
  int pos = atomicAdd(&meta[MI_CURSOR + e], 1);
  meta[MI_ROWTOK + pos] = idx >> 1;
  ((float*)(meta + MI_ROWW))[pos] = w;
}

// ---------------- gather: x rows -> bf16 Xg in expert order ----------------
__global__ __launch_bounds__(256) void gather_kernel(
    const float* __restrict__ x, short* __restrict__ Xg,
    const int* __restrict__ meta)
{
  int r = blockIdx.x;
  int tok = meta[MI_ROWTOK + r];                       // 0 for pad rows (weight 0)
  int i = threadIdx.x * 8;
  const float* src = x + (size_t)tok * Hdim + i;
  float4 a = *(const float4*)src;
  float4 b = *(const float4*)(src + 4);
  union { s8v v; unsigned short us[8]; } o;
  o.us[0] = f2bf(a.x); o.us[1] = f2bf(a.y); o.us[2] = f2bf(a.z); o.us[3] = f2bf(a.w);
  o.us[4] = f2bf(b.x); o.us[5] = f2bf(b.y); o.us[6] = f2bf(b.z); o.us[7] = f2bf(b.w);
  *(s8v*)(Xg + (size_t)r * Hdim + i) = o.v;
}

// ---------------- transpose-convert v2: T[e][n][k] (bf16) = W[e][k][n] (fp32) ----------------
__global__ __launch_bounds__(256) void convT_kernel(
    const float* __restrict__ W, short* __restrict__ T, int K, int N)
{
  __shared__ float lds[64 * 66];
  int ntn = N >> 6, ntk = K >> 6;
  int per_e = ntn * ntk;
  int e = blockIdx.x / per_e;
  int r = blockIdx.x % per_e;
  int tn = r % ntn, tk = r / ntn;
  const float* We = W + (size_t)e * K * N + (size_t)(tk << 6) * N + (tn << 6);
  short* Te = T + (size_t)e * K * N + (size_t)(tn << 6) * K + (tk << 6);
  int tid = threadIdx.x;

  int k = tid >> 4;            // 16 rows per pass
  int n4 = (tid & 15) << 2;
#pragma unroll
  for (int p = 0; p < 4; ++p) {
    int kk = (p << 4) + k;
    float4 v = *(const float4*)(We + (size_t)kk * N + n4);
    lds[(n4 + 0) * 66 + kk] = v.x;
    lds[(n4 + 1) * 66 + kk] = v.y;
    lds[(n4 + 2) * 66 + kk] = v.z;
    lds[(n4 + 3) * 66 + kk] = v.w;
  }
  __syncthreads();

  int n = tid >> 3;            // 32 rows per pass
  int kp = (tid & 7) << 3;
#pragma unroll
  for (int p = 0; p < 2; ++p) {
    int nn = (p << 5) + n;
    const float* row = &lds[nn * 66 + kp];
    uint4 o;
    o.x = pack2(row[0], row[1]);
    o.y = pack2(row[2], row[3]);
    o.z = pack2(row[4], row[5]);
    o.w = pack2(row[6], row[7]);
    *(uint4*)(Te + (size_t)nn * K + kp) = o;
  }
}

// ======== GEMMs: 128x128 tile, 4 waves, BK=64, ONE barrier-pair per 64-K ========
// LDS tiles [128][64] bf16 (16 KB each) with XOR 16B-slot swizzle:
// physical slot j of row R holds global k-chunk j^(R&7); staged via linear-dest
// global_load_lds with pre-swizzled GLOBAL source (rule #21); ds_read swizzles back.
// 2 blocks/CU cover the per-K-tile drain (R14 proved 1 block/CU loses 30%).

// ---------------- pass A: h = silu(Xg@Wg[e]) * (Xg@Wu[e]) -> bf16 Hbuf ----------------
__global__ __launch_bounds__(256, 2) void gateup_kernel(
    const short* __restrict__ Xg, const short* __restrict__ WgT,
    const short* __restrict__ WuT, short* __restrict__ Hbuf,
    const int* __restrict__ meta)
{
  const int NT = Idim / 128;                 // 44
  const int NWG = MTCAP * NT;                // 5984 = 8 * 748
  int bid = (blockIdx.x & 7) * (NWG / 8) + (blockIdx.x >> 3);  // XCD-bijective
  int chunk = bid / (8 * NT);
  int rem   = bid % (8 * NT);
  int mtile = chunk * 8 + (rem & 7);         // 8 M-tiles per chunk share weight panels
  int ntile = rem >> 3;
  if (mtile >= meta[MI_NTILES]) return;
  int e = meta[MI_TILEEXP + mtile];
  int n0 = ntile * 128;

  __shared__ short sA [128 * 64];            // 16 KB
  __shared__ short sBg[128 * 64];
  __shared__ short sBu[128 * 64];

  int tid = threadIdx.x;
  int lane = tid & 63, wv = tid >> 6;
  int wm = wv >> 1, wn = wv & 1;
  int lr = lane & 15, lg = lane >> 4;
  int ldst = wv * 512;                       // wave-uniform dest (shorts) within round

  // staging source: row-in-round = tid>>3 (0..31), pre-swizzled k-slot
  int srow = tid >> 3;
  int kc = ((tid & 7) ^ (srow & 7)) * 8;     // global k-chunk for physical slot tid&7
  const short* pA = Xg  + (size_t)(mtile * 128 + srow) * Hdim + kc;
  const short* pG = WgT + (size_t)e * Idim * Hdim + (size_t)(n0 + srow) * Hdim + kc;
  const short* pU = WuT + (size_t)e * Idim * Hdim + (size_t)(n0 + srow) * Hdim + kc;

  // swizzled fragment offsets: row R, k-half ks, chunk c = ks*4+lg -> slot c^(R&7)
  int aoff[4][2], boff[4][2];
#pragma unroll
  for (int mi = 0; mi < 4; ++mi) {
    int R = wm * 64 + mi * 16 + lr;
#pragma unroll
    for (int ks = 0; ks < 2; ++ks) aoff[mi][ks] = R * 64 + (((ks * 4 + lg) ^ (R & 7)) << 3);
  }
#pragma unroll
  for (int ni = 0; ni < 4; ++ni) {
    int R = wn * 64 + ni * 16 + lr;
#pragma unroll
    for (int ks = 0; ks < 2; ++ks) boff[ni][ks] = R * 64 + (((ks * 4 + lg) ^ (R & 7)) << 3);
  }

  f4v accg[4][4], accu[4][4];
  f4v z = {0.f, 0.f, 0.f, 0.f};
#pragma unroll
  for (int a1 = 0; a1 < 4; ++a1)
#pragma unroll
    for (int b1 = 0; b1 < 4; ++b1) { accg[a1][b1] = z; accu[a1][b1] = z; }

  for (int kt = 0; kt < Hdim / 64; ++kt) {   // 32 iters, 12 glds + 64 MFMA each
    size_t k0 = (size_t)kt * 64;
#pragma unroll
    for (int r = 0; r < 4; ++r) {            // 4 rounds x 32 rows = 128 rows per tile
      size_t go = (size_t)(r * 32) * Hdim + k0;
      int lo = r * 2048 + ldst;
      glds16(pA + go, &sA [lo]);
      glds16(pG + go, &sBg[lo]);
      glds16(pU + go, &sBu[lo]);
    }
    __syncthreads();

    s8v a[4][2];
#pragma unroll
    for (int mi = 0; mi < 4; ++mi)
#pragma unroll
      for (int ks = 0; ks < 2; ++ks)
        a[mi][ks] = *(const s8v*)&sA[aoff[mi][ks]];
#pragma unroll
    for (int ni = 0; ni < 4; ++ni) {
      s8v bg0 = *(const s8v*)&sBg[boff[ni][0]];
      s8v bg1 = *(const s8v*)&sBg[boff[ni][1]];
      s8v bu0 = *(const s8v*)&sBu[boff[ni][0]];
      s8v bu1 = *(const s8v*)&sBu[boff[ni][1]];
#pragma unroll
      for (int mi = 0; mi < 4; ++mi) {
        accg[mi][ni] = __builtin_amdgcn_mfma_f32_16x16x32_bf16(a[mi][0], bg0, accg[mi][ni], 0, 0, 0);
        accg[mi][ni] = __builtin_amdgcn_mfma_f32_16x16x32_bf16(a[mi][1], bg1, accg[mi][ni], 0, 0, 0);
        accu[mi][ni] = __builtin_amdgcn_mfma_f32_16x16x32_bf16(a[mi][0], bu0, accu[mi][ni], 0, 0, 0);
        accu[mi][ni] = __builtin_amdgcn_mfma_f32_16x16x32_bf16(a[mi][1], bu1, accu[mi][ni], 0, 0, 0);
      }
    }
    __syncthreads();
  }

  // epilogue: h = silu(g)*u -> bf16  (C/D: col=lane&15, row=(lane>>4)*4+r)
  int row0 = mtile * 128 + wm * 64;
#pragma unroll
  for (int mi = 0; mi < 4; ++mi) {
#pragma unroll
    for (int ni = 0; ni < 4; ++ni) {
      int col = n0 + wn * 64 + ni * 16 + lr;
#pragma unroll
      for (int r = 0; r < 4; ++r) {
        int row = row0 + mi * 16 + lg * 4 + r;
        float g = accg[mi][ni][r], u = accu[mi][ni][r];
        float h = g / (1.f + __expf(-g)) * u;
        Hbuf[(size_t)row * Idim + col] = (short)f2bf(h);
      }
    }
  }
}

// ---------------- pass B: y = Hbuf@Wd[e]; out[token] += w*y (atomic) ----------------
__global__ __launch_bounds__(256, 2) void down_kernel(
    const short* __restrict__ Hbuf, const short* __restrict__ WdT,
    float* __restrict__ out, const int* __restrict__ meta)
{
  const int NT = Hdim / 128;                 // 16
  const int NWG = MTCAP * NT;                // 2176 = 8 * 272
  int bid = (blockIdx.x & 7) * (NWG / 8) + (blockIdx.x >> 3);  // XCD-bijective
  int chunk = bid / (8 * NT);
  int rem   = bid % (8 * NT);
  int mtile = chunk * 8 + (rem & 7);
  int ntile = rem >> 3;
  if (mtile >= meta[MI_NTILES]) return;
  int e = meta[MI_TILEEXP + mtile];
  int n0 = ntile * 128;

  __shared__ short sA[128 * 64];
  __shared__ short sB[128 * 64];

  int tid = threadIdx.x;
  int lane = tid & 63, wv = tid >> 6;
  int wm = wv >> 1, wn = wv & 1;
  int lr = lane & 15, lg = lane >> 4;
  int ldst = wv * 512;

  int srow = tid >> 3;
  int kc = ((tid & 7) ^ (srow & 7)) * 8;
  const short* pA = Hbuf + (size_t)(mtile * 128 + srow) * Idim + kc;
  const short* pB = WdT  + (size_t)e * Hdim * Idim + (size_t)(n0 + srow) * Idim + kc;

  int aoff[4][2], boff[4][2];
#pragma unroll
  for (int mi = 0; mi < 4; ++mi) {
    int R = wm * 64 + mi * 16 + lr;
#pragma unroll
    for (int ks = 0; ks < 2; ++ks) aoff[mi][ks] = R * 64 + (((ks * 4 + lg) ^ (R & 7)) << 3);
  }
#pragma unroll
  for (int ni = 0; ni < 4; ++ni) {
    int R = wn * 64 + ni * 16 + lr;
#pragma unroll
    for (int ks = 0; ks < 2; ++ks) boff[ni][ks] = R * 64 + (((ks * 4 + lg) ^ (R & 7)) << 3);
  }

  f4v acc[4][4];
  f4v z = {0.f, 0.f, 0.f, 0.f};
#pragma unroll
  for (int a1 = 0; a1 < 4; ++a1)
#pragma unroll
    for (int b1 = 0; b1 < 4; ++b1) acc[a1][b1] = z;

  for (int kt = 0; kt < Idim / 64; ++kt) {   // 88 iters
    size_t k0 = (size_t)kt * 64;
#pragma unroll
    for (int r = 0; r < 4; ++r) {
      size_t go = (size_t)(r * 32) * Idim + k0;
      int lo = r * 2048 + ldst;
      glds16(pA + go, &sA[lo]);
      glds16(pB + go, &sB[lo]);
    }
    __syncthreads();

    s8v a[4][2];
#pragma unroll
    for (int mi = 0; mi < 4; ++mi)
#pragma unroll
      for (int ks = 0; ks < 2; ++ks)
        a[mi][ks] = *(const s8v*)&sA[aoff[mi][ks]];
#pragma unroll
    for (int ni = 0; ni < 4; ++ni) {
      s8v b0 = *(const s8v*)&sB[boff[ni][0]];
      s8v b1 = *(const s8v*)&sB[boff[ni][1]];
#pragma unroll
      for (int mi = 0; mi < 4; ++mi) {
        acc[mi][ni] = __builtin_amdgcn_mfma_f32_16x16x32_bf16(a[mi][0], b0, acc[mi][ni], 0, 0, 0);
        acc[mi][ni] = __builtin_amdgcn_mfma_f32_16x16x32_bf16(a[mi][1], b1, acc[mi][ni], 0, 0, 0);
      }
    }
    __syncthreads();
  }

  int row0 = mtile * 128 + wm * 64;
  const int* rowtok = meta + MI_ROWTOK;
  const float* roww = (const float*)(meta + MI_ROWW);
#pragma unroll
  for (int mi = 0; mi < 4; ++mi) {
#pragma unroll
    for (int r = 0; r < 4; ++r) {
      int row = row0 + mi * 16 + lg * 4 + r;
      int tok = rowtok[row];
      float w = roww[row];                    // 0 for pad rows
      float* orow = out + (size_t)tok * Hdim + n0 + wn * 64 + lr;
#pragma unroll
      for (int ni = 0; ni < 4; ++ni)
        atomicAdd(orow + ni * 16, w * acc[mi][ni][r]);
    }
  }
}

extern "C" void kernel_launch(void* const* d_in, const int* in_sizes, int n_in,
                              void* d_out, int out_size, void* d_ws, size_t ws_size,
                              hipStream_t stream)
{
  (void)in_sizes; (void)n_in; (void)out_size; (void)ws_size;
  const float* x  = (const float*)d_in[0];
  const float* Wr = (const float*)d_in[1];
  const float* br = (const float*)d_in[2];
  const float* Wg = (const float*)d_in[3];
  const float* Wu = (const float*)d_in[4];
  const float* Wd = (const float*)d_in[5];
  float* out = (float*)d_out;
  float* logits = out + (size_t)NTOK * Hdim;        // output 1 region
  int* meta = (int*)d_ws;
  short* Xg   = (short*)((char*)d_ws + XG_OFF);
  short* WgT  = (short*)((char*)d_ws + WGT_OFF);
  short* WuT  = (short*)((char*)d_ws + WUT_OFF);
  short* WdT  = (short*)((char*)d_ws + WDT_OFF);    // aliases WgT
  short* Hbuf = (short*)((char*)d_ws + HB_OFF);

  hipMemsetAsync(d_out, 0, (size_t)NTOK * Hdim * sizeof(float), stream); // atomics accumulate
  hipMemsetAsync(d_ws, 0, META_ZERO_BYTES, stream);                      // counts + row tok/weight

  const int convBlocks = NEXP * (Idim / 64) * (Hdim / 64);               // 22528

  router_kernel <<<NTOK / 4, 256, 0, stream>>>(x, Wr, br, logits, meta);
  offsets_kernel<<<1, 256, 0, stream>>>(meta);
  scatter_kernel<<<NROW / 256, 256, 0, stream>>>(meta);
  gather_kernel <<<RCAP, 256, 0, stream>>>(x, Xg, meta);
  convT_kernel  <<<convBlocks, 256, 0, stream>>>(Wg, WgT, Hdim, Idim);
  convT_kernel  <<<convBlocks, 256, 0, stream>>>(Wu, WuT, Hdim, Idim);
  gateup_kernel <<<MTCAP * (Idim / 128), 256, 0, stream>>>(Xg, WgT, WuT, Hbuf, meta);
  convT_kernel  <<<convBlocks, 256, 0, stream>>>(Wd, WdT, Idim, Hdim);   // after gateup (aliases WgT)
  down_kernel   <<<MTCAP * (Hdim / 128), 256, 0, stream>>>(Hbuf, WdT, out, meta);
}